// Round 10
// baseline (268.925 us; speedup 1.0000x reference)
//
#include <hip/hip_runtime.h>
#include <hip/hip_bf16.h>

#define N_NODES 100000
#define N_EDGES 3200000
#define N_GRAPHS 512
#define HID 64
#define OUT_DIM 10

#define NPB 64                  // nodes per dst-bucket (pow2: /-> >>6, %-> &63)
#define NB  1563                // ceil(N_NODES / NPB)
#define CAP 2432                // edges/bucket capacity (mean 2047, sd ~45 -> +8.5 sigma)

// ---------------------------------------------------------------------------
// K1: partition edges into dst-range buckets. Packed word: (dlocal<<24)|src.
// Block-aggregated cursors: LDS histogram -> 1 ranged global atomic per
// (block,bucket) -> LDS cursors -> append. 8 edges/thread.
__global__ __launch_bounds__(256) void k_part(const int4* __restrict__ src4,
                                              const int4* __restrict__ dst4,
                                              unsigned* __restrict__ bcur,
                                              unsigned* __restrict__ ebuf) {
    __shared__ unsigned hist[NB];
    __shared__ unsigned curs[NB];
    int tid = threadIdx.x;
    for (int i = tid; i < NB; i += 256) hist[i] = 0;
    __syncthreads();
    int4 s[2], d[2];
    int base4 = (blockIdx.x * 256 + tid) * 2;
    #pragma unroll
    for (int k = 0; k < 2; k++) {
        int i4 = base4 + k;
        if (i4 < N_EDGES / 4) { s[k] = src4[i4]; d[k] = dst4[i4]; }
        else { s[k] = make_int4(-1, -1, -1, -1); d[k] = make_int4(0, 0, 0, 0); }
    }
    #pragma unroll
    for (int k = 0; k < 2; k++) {
        if (s[k].x >= 0) {
            atomicAdd(&hist[d[k].x >> 6], 1u);
            atomicAdd(&hist[d[k].y >> 6], 1u);
            atomicAdd(&hist[d[k].z >> 6], 1u);
            atomicAdd(&hist[d[k].w >> 6], 1u);
        }
    }
    __syncthreads();
    for (int b = tid; b < NB; b += 256) {
        unsigned c = hist[b];
        curs[b] = c ? atomicAdd(&bcur[b], c) : 0u;
    }
    __syncthreads();
    #pragma unroll
    for (int k = 0; k < 2; k++) {
        if (s[k].x >= 0) {
            int ss[4] = { s[k].x, s[k].y, s[k].z, s[k].w };
            int dd[4] = { d[k].x, d[k].y, d[k].z, d[k].w };
            #pragma unroll
            for (int m = 0; m < 4; m++) {
                int b = dd[m] >> 6;
                unsigned dl = (unsigned)(dd[m] & 63);
                unsigned slot = atomicAdd(&curs[b], 1u);
                ebuf[(size_t)b * CAP + slot] = (dl << 24) | (unsigned)ss[m];
            }
        }
    }
}

// ---------------------------------------------------------------------------
// K2: per-bucket degree histogram in LDS -> deg, dinv, g1.
__global__ __launch_bounds__(256) void k_buck1(const unsigned* __restrict__ ebuf,
                                               const unsigned* __restrict__ bcur,
                                               const float* __restrict__ x,
                                               unsigned* __restrict__ deg,
                                               float* __restrict__ dinv,
                                               float* __restrict__ g1) {
    __shared__ unsigned cnt[NPB];
    int b = blockIdx.x, tid = threadIdx.x;
    if (tid < NPB) cnt[tid] = 0;
    __syncthreads();
    int ec = (int)bcur[b];
    const unsigned* eb = ebuf + (size_t)b * CAP;
    for (int i = tid; i < ec; i += 256)
        atomicAdd(&cnt[eb[i] >> 24], 1u);
    __syncthreads();
    int n0 = b * NPB;
    int nn = min(NPB, N_NODES - n0);
    if (tid < nn) {
        unsigned c = cnt[tid];
        float dn = 1.0f / sqrtf((float)c + 1.0f);   // +1: self loop
        deg[n0 + tid] = c;
        dinv[n0 + tid] = dn;
        g1[n0 + tid] = dn * x[n0 + tid];
    }
}

// ---------------------------------------------------------------------------
// K3: per-bucket layer-1 scalar aggregation in LDS -> sd = (s, dinv).
__global__ __launch_bounds__(256) void k_buck2(const unsigned* __restrict__ ebuf,
                                               const unsigned* __restrict__ bcur,
                                               const float* __restrict__ g1,
                                               const float* __restrict__ dinv,
                                               const float* __restrict__ x,
                                               float2* __restrict__ sd) {
    __shared__ float sacc[NPB];
    int b = blockIdx.x, tid = threadIdx.x;
    if (tid < NPB) sacc[tid] = 0.f;
    __syncthreads();
    int ec = (int)bcur[b];
    const unsigned* eb = ebuf + (size_t)b * CAP;
    for (int i = tid; i < ec; i += 256) {
        unsigned w = eb[i];
        atomicAdd(&sacc[w >> 24], g1[w & 0x00FFFFFFu]);
    }
    __syncthreads();
    int n0 = b * NPB;
    int nn = min(NPB, N_NODES - n0);
    if (tid < nn) {
        float dn = dinv[n0 + tid];
        float s = dn * (sacc[tid] + dn * x[n0 + tid]);
        sd[n0 + tid] = make_float2(s, dn);
    }
}

// ---------------------------------------------------------------------------
// K4: per-bucket layer-2 + fused pooling. Software-pipelined per-node gather
// (prefetch node n+4's edge batch during node n's compute), W2 column held in
// VGPRs (launch_bounds(256,4) caps at 128 VGPR so it stays resident),
// b128 2-edge broadcast reads. Zero per-edge atomics.
__global__ __launch_bounds__(256, 4) void k_buck3(const unsigned* __restrict__ ebuf,
                                                  const unsigned* __restrict__ bcur,
                                                  const unsigned* __restrict__ deg,
                                                  const float2* __restrict__ sd,
                                                  const int* __restrict__ batch,
                                                  const float* __restrict__ W1,
                                                  const float* __restrict__ b1,
                                                  const float* __restrict__ W2,
                                                  const float* __restrict__ b2,
                                                  float* __restrict__ pooled) {
    __shared__ unsigned sorted[CAP];     // 9728 B
    __shared__ float2 stage[256];        // 4 waves x 64, wave-private slices
    __shared__ int offs[NPB + 1];
    __shared__ unsigned curs[NPB];
    int b = blockIdx.x, tid = threadIdx.x;
    int lane = tid & 63, wv = tid >> 6;
    int n0 = b * NPB;
    int nn = min(NPB, N_NODES - n0);
    if (tid == 0) {                      // serial 64-scan: negligible
        int r = 0;
        for (int i = 0; i < nn; i++) { offs[i] = r; curs[i] = (unsigned)r; r += (int)deg[n0 + i]; }
        offs[nn] = r;
    }
    float w2col[HID];                    // register-resident W2 column
    #pragma unroll
    for (int j = 0; j < HID; j++) w2col[j] = W2[j * HID + lane];
    float w1 = W1[lane], bb1 = b1[lane], bb2 = b2[lane];
    __syncthreads();
    int ec = (int)bcur[b];
    const unsigned* eb = ebuf + (size_t)b * CAP;
    for (int i = tid; i < ec; i += 256) {           // counting-sort scatter
        unsigned w = eb[i];
        unsigned slot = atomicAdd(&curs[w >> 24], 1u);
        sorted[slot] = w;
    }
    __syncthreads();
    float2* st = stage + wv * 64;
    const float4* stv = (const float4*)st;
    int curg = -1;
    float pacc1 = 0.f, pacc2 = 0.f;

    // prefetch helper: first <=64-edge batch of node n into registers
    auto fetchv = [&](int n) -> float2 {
        float2 v = make_float2(0.f, 0.f);
        if (n < nn) {
            int lo = offs[n];
            int m = offs[n + 1] - lo; if (m > 64) m = 64;
            if (lane < m) v = sd[sorted[lo + lane] & 0x00FFFFFFu];
        }
        return v;
    };

    float2 vcur = fetchv(wv);
    for (int n = wv; n < nn; n += 4) {
        float2 vnext = fetchv(n + 4);    // hides L2 gather under compute below
        int lo = offs[n], hi = offs[n + 1];
        int m = hi - lo; if (m > 64) m = 64;
        st[lane] = vcur;                 // wave-private; DS in-order per wave
        float acca = 0.f, accb = 0.f;
        int k = 0;
        for (; k + 1 < m; k += 2) {      // 2 edges per ds_read_b128
            float4 e = stv[k >> 1];
            acca = fmaf(e.y, fmaxf(fmaf(e.x, w1, bb1), 0.f), acca);
            accb = fmaf(e.w, fmaxf(fmaf(e.z, w1, bb1), 0.f), accb);
        }
        if (k < m) {
            float2 e0 = st[k];
            acca = fmaf(e0.y, fmaxf(fmaf(e0.x, w1, bb1), 0.f), acca);
        }
        for (int base = lo + 64; base < hi; base += 64) {   // slow path (deg>64, rare)
            int mm = hi - base; if (mm > 64) mm = 64;
            float2 v = make_float2(0.f, 0.f);
            if (lane < mm) v = sd[sorted[base + lane] & 0x00FFFFFFu];
            st[lane] = v;
            int kk = 0;
            for (; kk + 1 < mm; kk += 2) {
                float4 e = stv[kk >> 1];
                acca = fmaf(e.y, fmaxf(fmaf(e.x, w1, bb1), 0.f), acca);
                accb = fmaf(e.w, fmaxf(fmaf(e.z, w1, bb1), 0.f), accb);
            }
            if (kk < mm) {
                float2 e0 = st[kk];
                acca = fmaf(e0.y, fmaxf(fmaf(e0.x, w1, bb1), 0.f), acca);
            }
        }
        float2 self = sd[n0 + n];
        float t = fmaxf(fmaf(self.x, w1, bb1), 0.f);       // = x1[n][lane]
        float a = self.y * (acca + accb + self.y * t);     // agg[n][lane]
        float acc2a = bb2, acc2b = 0.f;
        #pragma unroll
        for (int j = 0; j < HID; j += 2) {                 // readlane matvec
            float aj0 = __int_as_float(__builtin_amdgcn_readlane(__float_as_int(a), j));
            float aj1 = __int_as_float(__builtin_amdgcn_readlane(__float_as_int(a), j + 1));
            acc2a = fmaf(aj0, w2col[j], acc2a);
            acc2b = fmaf(aj1, w2col[j + 1], acc2b);
        }
        float x2v = fmaxf(acc2a + acc2b, 0.f);             // = x2[n][lane]
        int g = batch[n0 + n];                             // uniform scalar load
        if (g != curg) {
            if (curg >= 0) {
                atomicAdd(&pooled[curg * 2 * HID + lane], pacc1);
                atomicAdd(&pooled[curg * 2 * HID + HID + lane], pacc2);
            }
            curg = g; pacc1 = 0.f; pacc2 = 0.f;
        }
        pacc1 += t;
        pacc2 += x2v;
        vcur = vnext;
    }
    if (curg >= 0) {
        atomicAdd(&pooled[curg * 2 * HID + lane], pacc1);
        atomicAdd(&pooled[curg * 2 * HID + HID + lane], pacc2);
    }
}

// ---------------------------------------------------------------------------
// K5: head: pooled/cnt -> 128x10 linear. One block (128 thr) per graph.
// Graph boundaries via binary search on sorted batch (kills k_bounds).
__global__ __launch_bounds__(128) void k_head(const float* __restrict__ pooled,
                                              const int* __restrict__ batch,
                                              const float* __restrict__ Wl,
                                              const float* __restrict__ bl,
                                              float* __restrict__ out) {
    int g = blockIdx.x;
    int t = threadIdx.x;
    int lo1 = 0, hi1 = N_NODES;
    while (lo1 < hi1) { int mid = (lo1 + hi1) >> 1; if (batch[mid] < g) lo1 = mid + 1; else hi1 = mid; }
    int lo2 = lo1, hi2 = N_NODES;
    while (lo2 < hi2) { int mid = (lo2 + hi2) >> 1; if (batch[mid] < g + 1) lo2 = mid + 1; else hi2 = mid; }
    float denom = fmaxf((float)(lo2 - lo1), 1.f);
    __shared__ float pl[2 * HID];
    pl[t] = pooled[g * 2 * HID + t] / denom;
    __syncthreads();
    if (t < OUT_DIM) {
        float r = bl[t];
        #pragma unroll 16
        for (int j = 0; j < 2 * HID; j++) r = fmaf(pl[j], Wl[j * OUT_DIM + t], r);
        out[g * OUT_DIM + t] = r;
    }
}

// ---------------------------------------------------------------------------
extern "C" void kernel_launch(void* const* d_in, const int* in_sizes, int n_in,
                              void* d_out, int out_size, void* d_ws, size_t ws_size,
                              hipStream_t stream) {
    const float* x      = (const float*)d_in[0];
    const int*   ei     = (const int*)d_in[1];           // (2, E) int32
    const int*   batch  = (const int*)d_in[2];
    const float* W1     = (const float*)d_in[3];
    const float* b1     = (const float*)d_in[4];
    const float* W2     = (const float*)d_in[5];
    const float* b2     = (const float*)d_in[6];
    const float* Wl     = (const float*)d_in[7];
    const float* bl     = (const float*)d_in[8];
    float* out = (float*)d_out;

    const int* src = ei;
    const int* dst = ei + N_EDGES;

    // workspace carve-up (256B aligned)
    char* p = (char*)d_ws;
    auto alloc = [&](size_t bytes) { void* r = (void*)p; p += (bytes + 255) & ~(size_t)255; return r; };
    unsigned* bcur   = (unsigned*)alloc(NB * 4);
    unsigned* ebuf   = (unsigned*)alloc((size_t)NB * CAP * 4);   // 15.2 MB
    unsigned* deg    = (unsigned*)alloc(N_NODES * 4);
    float*    dinv   = (float*)alloc(N_NODES * 4);
    float*    g1     = (float*)alloc(N_NODES * 4);
    float2*   sd     = (float2*)alloc((size_t)N_NODES * 8);
    float*    pooled = (float*)alloc((size_t)N_GRAPHS * 2 * HID * 4);

    hipMemsetAsync(bcur, 0, NB * 4, stream);
    hipMemsetAsync(pooled, 0, (size_t)N_GRAPHS * 2 * HID * 4, stream);

    const int TB = 256;
    int pbl = (N_EDGES / 8 + TB - 1) / TB;    // 8 edges per thread

    k_part <<<pbl, TB, 0, stream>>>((const int4*)src, (const int4*)dst, bcur, ebuf);
    k_buck1<<<NB, TB, 0, stream>>>(ebuf, bcur, x, deg, dinv, g1);
    k_buck2<<<NB, TB, 0, stream>>>(ebuf, bcur, g1, dinv, x, sd);
    k_buck3<<<NB, TB, 0, stream>>>(ebuf, bcur, deg, sd, batch, W1, b1, W2, b2, pooled);
    k_head <<<N_GRAPHS, 128, 0, stream>>>(pooled, batch, Wl, bl, out);
}